// Round 4
// baseline (71.080 us; speedup 1.0000x reference)
//
#include <hip/hip_runtime.h>
#include <math.h>

#define BATCH  8192
#define DIM    128
#define NTREES 512
#define UNITS  8
#define RB 64
#define NROWBLK (BATCH/RB)         // 128
#define NTREEBLK 16

typedef __attribute__((ext_vector_type(8))) __bf16 bf16x8;
typedef __attribute__((ext_vector_type(4))) float f32x4;

static __device__ inline unsigned short f2bf(float v) {
  __bf16 h = (__bf16)v;
  return *(unsigned short*)&h;
}

// ---------------------------------------------------------------------------
// Fused prep:
//  blocks [0,4096):    sparsemax per (tree,d) -> Wfrag A-fragment stream (bf16)
//  blocks [4096,12288): inputs -> bf16 row-swizzled Ximg
//  blocks [12288,16384): response -> Rb B-fragment stream (new kg bijection:
//                        tree = lane-group G>>1, bit4 = ks>>1)
// ---------------------------------------------------------------------------
__global__ __launch_bounds__(128) void prep_all(
    const float* __restrict__ logits, const float* __restrict__ thr,
    const float* __restrict__ logtemp, const float* __restrict__ inputs,
    const float* __restrict__ resp,
    unsigned short* __restrict__ Wfrag, unsigned short* __restrict__ Ximg,
    unsigned short* __restrict__ Rb, float* __restrict__ biasPad)
{
  const int b = blockIdx.x, tid = threadIdx.x;
  if (b < 4096) {
    const int t = b >> 3, d = b & 7;
    const int tb = t >> 5, sub = (t >> 4) & 1, tloc = t & 15;
    const int slotL = tloc * 8 + d;                  // slot within 128-slot subtile
    const int w = slotL >> 5, p = (slotL >> 4) & 1, ln = slotL & 15;
    const int ks = tid >> 5, G = (tid >> 3) & 3, j = tid & 7;
    const size_t wi =
        ((size_t)(((((tb*2 + sub)*4 + w)*2 + p)*4) + ks)*64 + (G*16 + ln))*8 + j;
    if (d >= 6) {
      Wfrag[wi] = 0;
      if (tid == 0) biasPad[t*8 + d] = 0.f;
      return;
    }
    __shared__ float z[128], rc[128], rs[128];
    float zi = logits[((size_t)tid * NTREES + t) * 6 + d];
    z[tid] = zi;
    __syncthreads();
    float k = 0.f, S = 0.f;
    for (int q = 0; q < 128; ++q) {
      float zq = z[q];
      if (zq >= zi) { k += 1.f; S += zq; }
    }
    bool sup = (1.f + k * zi) > S;
    rc[tid] = sup ? 1.f : 0.f;
    rs[tid] = sup ? zi : 0.f;
    __syncthreads();
    for (int off = 64; off > 0; off >>= 1) {
      if (tid < off) { rc[tid] += rc[tid + off]; rs[tid] += rs[tid + off]; }
      __syncthreads();
    }
    float tau = (rs[0] - 1.f) / rc[0];
    float et = expf(-logtemp[t*6 + d]);
    Wfrag[wi] = f2bf(fmaxf(zi - tau, 0.f) * et);
    if (tid == 0) biasPad[t*8 + d] = -thr[t*6 + d] * et;
  } else if (b < 12288) {
    const int r = b - 4096;
    float v = inputs[(size_t)r * DIM + tid];
    int col = ((tid * 2) ^ ((r & 7) << 4)) >> 1;
    Ximg[(size_t)r * DIM + col] = f2bf(v);
  } else {
    const int idx = (b - 12288) * 128 + tid;         // < 524288
    const int j = idx & 7, lane = (idx >> 3) & 63;
    const int ks = (idx >> 9) & 3, pg = idx >> 11;
    const int G = lane >> 4, u = lane & 15;
    const int tree = pg * 2 + (G >> 1);              // tree from lane group!
    const int leaf = j + ((G & 1) << 3) + ((ks >> 1) << 4) + ((ks & 1) << 5);
    float v = (u < UNITS) ? resp[((size_t)tree*UNITS + u)*64 + leaf] : 0.f;
    Rb[idx] = f2bf(v);
  }
}

// ---------------------------------------------------------------------------
// Main: 64 batch rows x 32 trees per block, 4 waves.  X tile in LDS (17 KB
// total LDS); W and R read directly from global fragment streams (L2).
// Swapped GEMM1 -> fv in-lane for batch col ln; per-lane gates of OWN tree
// only (kg bijection), leaf products in-register, GEMM2 via MFMA.
// ---------------------------------------------------------------------------
__global__ __launch_bounds__(256, 4) void odt_main(
    const unsigned short* __restrict__ Ximg, const unsigned short* __restrict__ Wfrag,
    const float* __restrict__ biasPad, const unsigned short* __restrict__ Rb,
    float* __restrict__ partial)
{
  __shared__ __align__(16) char pool[17408];
  char* Xl = pool;                        // 16384 B
  float* biasl = (float*)(pool + 16384);  // 1024 B
  float* outred = (float*)pool;           // aliases Xl after final barrier (8 KB)

  const int tid = threadIdx.x;
  const int lane = tid & 63;
  const int w = tid >> 6;       // wave 0..3
  const int G = lane >> 4;      // 0..3
  const int ln = lane & 15;
  const int bx = blockIdx.x, tb = blockIdx.y;

  {
    const float4* src = (const float4*)(Ximg + (size_t)bx * RB * DIM);
    float4* dst = (float4*)Xl;
    #pragma unroll
    for (int it = 0; it < 4; ++it) dst[tid + it * 256] = src[tid + it * 256];
  }
  biasl[tid] = biasPad[(size_t)tb * 256 + tid];
  __syncthreads();

  f32x4 out[4];
  #pragma unroll
  for (int nt = 0; nt < 4; ++nt)
    #pragma unroll
    for (int r = 0; r < 4; ++r) out[nt][r] = 0.f;

  const bool hiHalf = (G & 1);

  for (int sub = 0; sub < 2; ++sub) {
    // ---- A fragments straight from global (L2-resident stream) ----
    bf16x8 Afr[2][4];
    const bf16x8* wf =
        (const bf16x8*)Wfrag + ((size_t)((tb*2 + sub)*4 + w) * 8) * 64;
    #pragma unroll
    for (int p = 0; p < 2; ++p)
      #pragma unroll
      for (int ks = 0; ks < 4; ++ks)
        Afr[p][ks] = wf[(p*4 + ks)*64 + lane];

    // ---- GEMM1: fv[slot][batch] ----
    f32x4 c1[2][4];
    #pragma unroll
    for (int p = 0; p < 2; ++p)
      #pragma unroll
      for (int nt = 0; nt < 4; ++nt)
        #pragma unroll
        for (int r = 0; r < 4; ++r) c1[p][nt][r] = 0.f;

    #pragma unroll
    for (int nt = 0; nt < 4; ++nt) {
      bf16x8 Bfr[4];
      #pragma unroll
      for (int ks = 0; ks < 4; ++ks) {
        int row = nt*16 + ln;
        int byte = row*256 + ((ks*64 + G*16) ^ ((row & 7) << 4));
        Bfr[ks] = *(const bf16x8*)(Xl + byte);
      }
      #pragma unroll
      for (int p = 0; p < 2; ++p)
        #pragma unroll
        for (int ks = 0; ks < 4; ++ks)
          c1[p][nt] = __builtin_amdgcn_mfma_f32_16x16x32_bf16(
              Afr[p][ks], Bfr[ks], c1[p][nt], 0, 0, 0);
    }

    // ---- epilogue: own-tree gates -> leaf fragments -> GEMM2 ----
    #pragma unroll
    for (int p = 0; p < 2; ++p) {
      const int pg = tb*16 + sub*8 + 2*w + p;
      bf16x8 B2[4];
      #pragma unroll
      for (int ks = 0; ks < 4; ++ks)
        B2[ks] = ((const bf16x8*)Rb)[((size_t)pg*4 + ks)*64 + lane];
      const int treeloc = sub*16 + 4*w + 2*p + (G >> 1);
      float bv[6];
      #pragma unroll
      for (int d = 0; d < 6; ++d) bv[d] = biasl[treeloc*8 + d];

      #pragma unroll
      for (int nt = 0; nt < 4; ++nt) {
        // assemble own tree's 6 fv values (one xor16 half-merge)
        float fd[6];
        {
          float fva[4], fvb[4];
          #pragma unroll
          for (int r = 0; r < 4; ++r) {
            fva[r] = c1[p][nt][r];
            fvb[r] = __shfl_xor(c1[p][nt][r], 16);
          }
          #pragma unroll
          for (int r = 0; r < 4; ++r) fd[r] = hiHalf ? fvb[r] : fva[r];
          fd[4] = hiHalf ? fva[0] : fvb[0];
          fd[5] = hiHalf ? fva[1] : fvb[1];
        }
        float s[6], om[6];
        #pragma unroll
        for (int d = 0; d < 6; ++d) {
          float tl = fd[d] + bv[d];
          float sv = fminf(fmaxf(0.5f + 0.5f*tl, 0.f), 1.f);
          s[d] = sv; om[d] = 1.f - sv;
        }
        // depth 0-2 leaf products (bit=0 -> s, bit=1 -> om), folded with g3
        float q00 = s[0]*s[1],  q10 = om[0]*s[1];
        float q01 = s[0]*om[1], q11 = om[0]*om[1];
        float g3 = hiHalf ? om[3] : s[3];
        float s2g = s[2]*g3, o2g = om[2]*g3;
        float p3g[8];
        p3g[0]=q00*s2g; p3g[1]=q10*s2g; p3g[2]=q01*s2g; p3g[3]=q11*s2g;
        p3g[4]=q00*o2g; p3g[5]=q10*o2g; p3g[6]=q01*o2g; p3g[7]=q11*o2g;
        // ks -> (bit4=ks>>1, bit5=ks&1) common factors
        float c45[4];
        c45[0] = s[4]*s[5];  c45[1] = s[4]*om[5];
        c45[2] = om[4]*s[5]; c45[3] = om[4]*om[5];

        #pragma unroll
        for (int ks = 0; ks < 4; ++ks) {
          bf16x8 A;
          #pragma unroll
          for (int j = 0; j < 8; ++j) A[j] = (__bf16)(c45[ks] * p3g[j]);
          out[nt] = __builtin_amdgcn_mfma_f32_16x16x32_bf16(
              A, B2[ks], out[nt], 0, 0, 0);
        }
      }
    }
  }

  // ---- cross-wave reduction (outred aliases Xl; all Xl reads done) ----
  __syncthreads();
  if (ln < UNITS) {
    #pragma unroll
    for (int nt = 0; nt < 4; ++nt)
      #pragma unroll
      for (int r = 0; r < 4; ++r)
        outred[((size_t)w*64 + nt*16 + 4*G + r)*8 + ln] = out[nt][r];
  }
  __syncthreads();
  #pragma unroll
  for (int v = 0; v < 2; ++v) {
    int e = tid + v*256;               // 0..511 = row*8+u
    int row = e >> 3, u = e & 7;
    float sum = outred[(0*64 + row)*8 + u]
              + outred[(1*64 + row)*8 + u]
              + outred[(2*64 + row)*8 + u]
              + outred[(3*64 + row)*8 + u];
    partial[((size_t)tb*BATCH + bx*RB + row)*8 + u] = sum;
  }
}

// ---------------------------------------------------------------------------
// reduce over the 16 tree-blocks, scale by 1/512
// ---------------------------------------------------------------------------
__global__ __launch_bounds__(256) void odt_reduce(
    const float* __restrict__ partial, float* __restrict__ out)
{
  int i = blockIdx.x * 256 + threadIdx.x;   // 0..65535
  float s = 0.f;
  #pragma unroll
  for (int t = 0; t < NTREEBLK; ++t)
    s += partial[(size_t)t * BATCH * UNITS + i];
  out[i] = s * (1.f / NTREES);
}

extern "C" void kernel_launch(void* const* d_in, const int* in_sizes, int n_in,
                              void* d_out, int out_size, void* d_ws, size_t ws_size,
                              hipStream_t stream)
{
  const float* inputs   = (const float*)d_in[0];
  const float* logits   = (const float*)d_in[1];
  const float* thr      = (const float*)d_in[2];
  const float* logtemp  = (const float*)d_in[3];
  const float* response = (const float*)d_in[4];
  float* out = (float*)d_out;

  char* ws = (char*)d_ws;
  unsigned short* Wfrag = (unsigned short*)(ws);                // 1 MB
  unsigned short* Ximg  = (unsigned short*)(ws + (1<<20));      // 2 MB
  unsigned short* Rb    = (unsigned short*)(ws + (3<<20));      // 1 MB
  float* biasPad        = (float*)(ws + (4<<20));               // 16 KB
  float* partial        = (float*)(ws + (4<<20) + (1<<14));     // 4 MB

  hipLaunchKernelGGL(prep_all, dim3(16384), dim3(128), 0, stream,
                     logits, thr, logtemp, inputs, response,
                     Wfrag, Ximg, Rb, biasPad);
  hipLaunchKernelGGL(odt_main, dim3(NROWBLK, NTREEBLK), dim3(256), 0, stream,
                     Ximg, Wfrag, biasPad, Rb, partial);
  hipLaunchKernelGGL(odt_reduce, dim3(BATCH * UNITS / 256), dim3(256), 0, stream,
                     partial, out);
}

// Round 5
// 64.462 us; speedup vs baseline: 1.1027x; 1.1027x over previous
//
#include <hip/hip_runtime.h>
#include <math.h>

#define BATCH  8192
#define DIM    128
#define NTREES 512
#define UNITS  8
#define RB 64
#define NROWBLK (BATCH/RB)         // 128
#define NTREEBLK 16

typedef __attribute__((ext_vector_type(8))) __bf16 bf16x8;
typedef __attribute__((ext_vector_type(4))) float f32x4;

static __device__ inline unsigned short f2bf(float v) {
  __bf16 h = (__bf16)v;
  return *(unsigned short*)&h;
}

// ---------------------------------------------------------------------------
// Fused prep:
//  blocks [0,4096):    sparsemax per (tree,d) -> Wfrag A-fragment stream (bf16)
//  blocks [4096,12288): inputs -> bf16 row-swizzled Ximg
//  blocks [12288,16384): response -> Rb B-fragment stream (kg bijection:
//                        tree = lane-group G>>1, bit4 = ks>>1)
// ---------------------------------------------------------------------------
__global__ __launch_bounds__(128) void prep_all(
    const float* __restrict__ logits, const float* __restrict__ thr,
    const float* __restrict__ logtemp, const float* __restrict__ inputs,
    const float* __restrict__ resp,
    unsigned short* __restrict__ Wfrag, unsigned short* __restrict__ Ximg,
    unsigned short* __restrict__ Rb, float* __restrict__ biasPad)
{
  const int b = blockIdx.x, tid = threadIdx.x;
  if (b < 4096) {
    const int t = b >> 3, d = b & 7;
    const int tb = t >> 5, sub = (t >> 4) & 1, tloc = t & 15;
    const int slotL = tloc * 8 + d;                  // slot within 128-slot subtile
    const int w = slotL >> 5, p = (slotL >> 4) & 1, ln = slotL & 15;
    const int ks = tid >> 5, G = (tid >> 3) & 3, j = tid & 7;
    const size_t wi =
        ((size_t)(((((tb*2 + sub)*4 + w)*2 + p)*4) + ks)*64 + (G*16 + ln))*8 + j;
    if (d >= 6) {
      Wfrag[wi] = 0;
      if (tid == 0) biasPad[t*8 + d] = 0.f;
      return;
    }
    __shared__ float z[128], rc[128], rs[128];
    float zi = logits[((size_t)tid * NTREES + t) * 6 + d];
    z[tid] = zi;
    __syncthreads();
    float k = 0.f, S = 0.f;
    for (int q = 0; q < 128; ++q) {
      float zq = z[q];
      if (zq >= zi) { k += 1.f; S += zq; }
    }
    bool sup = (1.f + k * zi) > S;
    rc[tid] = sup ? 1.f : 0.f;
    rs[tid] = sup ? zi : 0.f;
    __syncthreads();
    for (int off = 64; off > 0; off >>= 1) {
      if (tid < off) { rc[tid] += rc[tid + off]; rs[tid] += rs[tid + off]; }
      __syncthreads();
    }
    float tau = (rs[0] - 1.f) / rc[0];
    float et = expf(-logtemp[t*6 + d]);
    Wfrag[wi] = f2bf(fmaxf(zi - tau, 0.f) * et);
    if (tid == 0) biasPad[t*8 + d] = -thr[t*6 + d] * et;
  } else if (b < 12288) {
    const int r = b - 4096;
    float v = inputs[(size_t)r * DIM + tid];
    int col = ((tid * 2) ^ ((r & 7) << 4)) >> 1;
    Ximg[(size_t)r * DIM + col] = f2bf(v);
  } else {
    const int idx = (b - 12288) * 128 + tid;         // < 524288
    const int j = idx & 7, lane = (idx >> 3) & 63;
    const int ks = (idx >> 9) & 3, pg = idx >> 11;
    const int G = lane >> 4, u = lane & 15;
    const int tree = pg * 2 + (G >> 1);              // tree from lane group
    const int leaf = j + ((G & 1) << 3) + ((ks >> 1) << 4) + ((ks & 1) << 5);
    float v = (u < UNITS) ? resp[((size_t)tree*UNITS + u)*64 + leaf] : 0.f;
    Rb[idx] = f2bf(v);
  }
}

// ---------------------------------------------------------------------------
// Main: 64 batch rows x 32 trees per block, 4 waves, 1-D grid of 2048 with an
// XCD-aware swizzle: xcd = wg&7 owns tree-blocks {2*xcd, 2*xcd+1}, so each
// XCD's L2 working set is Ximg (2MB) + its two W/Rb slices (~256KB) < 4MB.
// ---------------------------------------------------------------------------
__global__ __launch_bounds__(256, 4) void odt_main(
    const unsigned short* __restrict__ Ximg, const unsigned short* __restrict__ Wfrag,
    const float* __restrict__ biasPad, const unsigned short* __restrict__ Rb,
    float* __restrict__ partial)
{
  __shared__ __align__(16) char pool[17408];
  char* Xl = pool;                        // 16384 B
  float* biasl = (float*)(pool + 16384);  // 1024 B
  float* outred = (float*)pool;           // aliases Xl after final barrier (8 KB)

  const int tid = threadIdx.x;
  const int lane = tid & 63;
  const int w = tid >> 6;       // wave 0..3
  const int G = lane >> 4;      // 0..3
  const int ln = lane & 15;

  // XCD-grouping swizzle (bijective on [0,2048))
  const int wg = blockIdx.x;
  const int xcd = wg & 7, j5 = wg >> 3;
  const int tb = (xcd << 1) | (j5 >> 7);
  const int bx = j5 & 127;

  {
    const float4* src = (const float4*)(Ximg + (size_t)bx * RB * DIM);
    float4* dst = (float4*)Xl;
    #pragma unroll
    for (int it = 0; it < 4; ++it) dst[tid + it * 256] = src[tid + it * 256];
  }
  biasl[tid] = biasPad[(size_t)tb * 256 + tid];
  __syncthreads();

  f32x4 out[4];
  #pragma unroll
  for (int nt = 0; nt < 4; ++nt)
    #pragma unroll
    for (int r = 0; r < 4; ++r) out[nt][r] = 0.f;

  const bool hiHalf = (G & 1);

  #pragma unroll
  for (int sub = 0; sub < 2; ++sub) {
    // ---- A fragments straight from global (L2-resident stream) ----
    bf16x8 Afr[2][4];
    const bf16x8* wf =
        (const bf16x8*)Wfrag + ((size_t)((tb*2 + sub)*4 + w) * 8) * 64;
    #pragma unroll
    for (int p = 0; p < 2; ++p)
      #pragma unroll
      for (int ks = 0; ks < 4; ++ks)
        Afr[p][ks] = wf[(p*4 + ks)*64 + lane];

    // ---- GEMM1: fv[slot][batch] ----
    f32x4 c1[2][4];
    #pragma unroll
    for (int p = 0; p < 2; ++p)
      #pragma unroll
      for (int nt = 0; nt < 4; ++nt)
        #pragma unroll
        for (int r = 0; r < 4; ++r) c1[p][nt][r] = 0.f;

    #pragma unroll
    for (int nt = 0; nt < 4; ++nt) {
      bf16x8 Bfr[4];
      #pragma unroll
      for (int ks = 0; ks < 4; ++ks) {
        int row = nt*16 + ln;
        int byte = row*256 + ((ks*64 + G*16) ^ ((row & 7) << 4));
        Bfr[ks] = *(const bf16x8*)(Xl + byte);
      }
      #pragma unroll
      for (int p = 0; p < 2; ++p)
        #pragma unroll
        for (int ks = 0; ks < 4; ++ks)
          c1[p][nt] = __builtin_amdgcn_mfma_f32_16x16x32_bf16(
              Afr[p][ks], Bfr[ks], c1[p][nt], 0, 0, 0);
    }

    // ---- epilogue: own-tree gates -> leaf fragments -> GEMM2 ----
    #pragma unroll
    for (int p = 0; p < 2; ++p) {
      const int pg = tb*16 + sub*8 + 2*w + p;
      bf16x8 B2[4];
      #pragma unroll
      for (int ks = 0; ks < 4; ++ks)
        B2[ks] = ((const bf16x8*)Rb)[((size_t)pg*4 + ks)*64 + lane];
      const int treeloc = sub*16 + 4*w + 2*p + (G >> 1);
      float bv[6];
      #pragma unroll
      for (int d = 0; d < 6; ++d) bv[d] = biasl[treeloc*8 + d];

      #pragma unroll
      for (int nt = 0; nt < 4; ++nt) {
        // assemble own tree's 6 fv values (one xor16 half-merge)
        float fd[6];
        {
          float fva[4], fvb[4];
          #pragma unroll
          for (int r = 0; r < 4; ++r) {
            fva[r] = c1[p][nt][r];
            fvb[r] = __shfl_xor(c1[p][nt][r], 16);
          }
          #pragma unroll
          for (int r = 0; r < 4; ++r) fd[r] = hiHalf ? fvb[r] : fva[r];
          fd[4] = hiHalf ? fva[0] : fvb[0];
          fd[5] = hiHalf ? fva[1] : fvb[1];
        }
        float s[6], om[6];
        #pragma unroll
        for (int d = 0; d < 6; ++d) {
          float tl = fd[d] + bv[d];
          float sv = fminf(fmaxf(0.5f + 0.5f*tl, 0.f), 1.f);
          s[d] = sv; om[d] = 1.f - sv;
        }
        // depth 0-2 leaf products (bit=0 -> s, bit=1 -> om), folded with g3
        float q00 = s[0]*s[1],  q10 = om[0]*s[1];
        float q01 = s[0]*om[1], q11 = om[0]*om[1];
        float g3 = hiHalf ? om[3] : s[3];
        float s2g = s[2]*g3, o2g = om[2]*g3;
        float p3g[8];
        p3g[0]=q00*s2g; p3g[1]=q10*s2g; p3g[2]=q01*s2g; p3g[3]=q11*s2g;
        p3g[4]=q00*o2g; p3g[5]=q10*o2g; p3g[6]=q01*o2g; p3g[7]=q11*o2g;
        // ks -> (bit4=ks>>1, bit5=ks&1) common factors
        float c45[4];
        c45[0] = s[4]*s[5];  c45[1] = s[4]*om[5];
        c45[2] = om[4]*s[5]; c45[3] = om[4]*om[5];

        #pragma unroll
        for (int ks = 0; ks < 4; ++ks) {
          bf16x8 A;
          #pragma unroll
          for (int jj = 0; jj < 8; ++jj) A[jj] = (__bf16)(c45[ks] * p3g[jj]);
          out[nt] = __builtin_amdgcn_mfma_f32_16x16x32_bf16(
              A, B2[ks], out[nt], 0, 0, 0);
        }
      }
    }
  }

  // ---- cross-wave reduction (outred aliases Xl; all Xl reads done) ----
  __syncthreads();
  if (ln < UNITS) {
    #pragma unroll
    for (int nt = 0; nt < 4; ++nt)
      #pragma unroll
      for (int r = 0; r < 4; ++r)
        outred[((size_t)w*64 + nt*16 + 4*G + r)*8 + ln] = out[nt][r];
  }
  __syncthreads();
  #pragma unroll
  for (int v = 0; v < 2; ++v) {
    int e = tid + v*256;               // 0..511 = row*8+u
    int row = e >> 3, u = e & 7;
    float sum = outred[(0*64 + row)*8 + u]
              + outred[(1*64 + row)*8 + u]
              + outred[(2*64 + row)*8 + u]
              + outred[(3*64 + row)*8 + u];
    partial[((size_t)tb*BATCH + bx*RB + row)*8 + u] = sum;
  }
}

// ---------------------------------------------------------------------------
// reduce over the 16 tree-blocks, scale by 1/512
// ---------------------------------------------------------------------------
__global__ __launch_bounds__(256) void odt_reduce(
    const float* __restrict__ partial, float* __restrict__ out)
{
  int i = blockIdx.x * 256 + threadIdx.x;   // 0..65535
  float s = 0.f;
  #pragma unroll
  for (int t = 0; t < NTREEBLK; ++t)
    s += partial[(size_t)t * BATCH * UNITS + i];
  out[i] = s * (1.f / NTREES);
}

extern "C" void kernel_launch(void* const* d_in, const int* in_sizes, int n_in,
                              void* d_out, int out_size, void* d_ws, size_t ws_size,
                              hipStream_t stream)
{
  const float* inputs   = (const float*)d_in[0];
  const float* logits   = (const float*)d_in[1];
  const float* thr      = (const float*)d_in[2];
  const float* logtemp  = (const float*)d_in[3];
  const float* response = (const float*)d_in[4];
  float* out = (float*)d_out;

  char* ws = (char*)d_ws;
  unsigned short* Wfrag = (unsigned short*)(ws);                // 1 MB
  unsigned short* Ximg  = (unsigned short*)(ws + (1<<20));      // 2 MB
  unsigned short* Rb    = (unsigned short*)(ws + (3<<20));      // 1 MB
  float* biasPad        = (float*)(ws + (4<<20));               // 16 KB
  float* partial        = (float*)(ws + (4<<20) + (1<<14));     // 4 MB

  hipLaunchKernelGGL(prep_all, dim3(16384), dim3(128), 0, stream,
                     logits, thr, logtemp, inputs, response,
                     Wfrag, Ximg, Rb, biasPad);
  hipLaunchKernelGGL(odt_main, dim3(NROWBLK * NTREEBLK), dim3(256), 0, stream,
                     Ximg, Wfrag, biasPad, Rb, partial);
  hipLaunchKernelGGL(odt_reduce, dim3(BATCH * UNITS / 256), dim3(256), 0, stream,
                     partial, out);
}

// Round 6
// 50.543 us; speedup vs baseline: 1.4063x; 1.2754x over previous
//
#include <hip/hip_runtime.h>
#include <math.h>

#define BATCH  8192
#define DIM    128
#define NTREES 512
#define UNITS  8
#define RB 64
#define NROWBLK (BATCH/RB)         // 128
#define NTREEBLK 16

typedef __attribute__((ext_vector_type(8))) __bf16 bf16x8;
typedef __attribute__((ext_vector_type(4))) float f32x4;

static __device__ inline unsigned short f2bf(float v) {
  __bf16 h = (__bf16)v;
  return *(unsigned short*)&h;
}

// ---------------------------------------------------------------------------
// Fused prep:
//  blocks [0,4096):    sparsemax per (tree,d) -> Wfrag A-fragment stream (bf16)
//  blocks [4096,12288): inputs -> bf16 row-swizzled Ximg
//  blocks [12288,16384): response -> Rb B-fragment stream (kg bijection:
//                        tree = lane-group G>>1, bit4 = ks>>1)
// ---------------------------------------------------------------------------
__global__ __launch_bounds__(128) void prep_all(
    const float* __restrict__ logits, const float* __restrict__ thr,
    const float* __restrict__ logtemp, const float* __restrict__ inputs,
    const float* __restrict__ resp,
    unsigned short* __restrict__ Wfrag, unsigned short* __restrict__ Ximg,
    unsigned short* __restrict__ Rb, float* __restrict__ biasPad)
{
  const int b = blockIdx.x, tid = threadIdx.x;
  if (b < 4096) {
    const int t = b >> 3, d = b & 7;
    const int tb = t >> 5, sub = (t >> 4) & 1, tloc = t & 15;
    const int slotL = tloc * 8 + d;                  // slot within 128-slot subtile
    const int w = slotL >> 5, p = (slotL >> 4) & 1, ln = slotL & 15;
    const int ks = tid >> 5, G = (tid >> 3) & 3, j = tid & 7;
    const size_t wi =
        ((size_t)(((((tb*2 + sub)*4 + w)*2 + p)*4) + ks)*64 + (G*16 + ln))*8 + j;
    if (d >= 6) {
      Wfrag[wi] = 0;
      if (tid == 0) biasPad[t*8 + d] = 0.f;
      return;
    }
    __shared__ float z[128], rc[128], rs[128];
    float zi = logits[((size_t)tid * NTREES + t) * 6 + d];
    z[tid] = zi;
    __syncthreads();
    float k = 0.f, S = 0.f;
    for (int q = 0; q < 128; ++q) {
      float zq = z[q];
      if (zq >= zi) { k += 1.f; S += zq; }
    }
    bool sup = (1.f + k * zi) > S;
    rc[tid] = sup ? 1.f : 0.f;
    rs[tid] = sup ? zi : 0.f;
    __syncthreads();
    for (int off = 64; off > 0; off >>= 1) {
      if (tid < off) { rc[tid] += rc[tid + off]; rs[tid] += rs[tid + off]; }
      __syncthreads();
    }
    float tau = (rs[0] - 1.f) / rc[0];
    float et = expf(-logtemp[t*6 + d]);
    Wfrag[wi] = f2bf(fmaxf(zi - tau, 0.f) * et);
    if (tid == 0) biasPad[t*8 + d] = -thr[t*6 + d] * et;
  } else if (b < 12288) {
    const int r = b - 4096;
    float v = inputs[(size_t)r * DIM + tid];
    int col = ((tid * 2) ^ ((r & 7) << 4)) >> 1;
    Ximg[(size_t)r * DIM + col] = f2bf(v);
  } else {
    const int idx = (b - 12288) * 128 + tid;         // < 524288
    const int j = idx & 7, lane = (idx >> 3) & 63;
    const int ks = (idx >> 9) & 3, pg = idx >> 11;
    const int G = lane >> 4, u = lane & 15;
    const int tree = pg * 2 + (G >> 1);              // tree from lane group
    const int leaf = j + ((G & 1) << 3) + ((ks >> 1) << 4) + ((ks & 1) << 5);
    float v = (u < UNITS) ? resp[((size_t)tree*UNITS + u)*64 + leaf] : 0.f;
    Rb[idx] = f2bf(v);
  }
}

// ---------------------------------------------------------------------------
// Main: 64 batch rows x 32 trees per block, 4 waves.  p (M-tile) is now the
// OUTER loop so only one Afr[4]/c1[4] set is live at a time (~halves VGPR
// pressure); launch_bounds (256,2) gives the allocator 256 regs -> no spill.
// XCD swizzle keeps each XCD's L2 set to Ximg + 2 tree-block slices (<4MB).
// ---------------------------------------------------------------------------
__global__ __launch_bounds__(256, 2) void odt_main(
    const unsigned short* __restrict__ Ximg, const unsigned short* __restrict__ Wfrag,
    const float* __restrict__ biasPad, const unsigned short* __restrict__ Rb,
    float* __restrict__ partial)
{
  __shared__ __align__(16) char pool[17408];
  char* Xl = pool;                        // 16384 B
  float* biasl = (float*)(pool + 16384);  // 1024 B
  float* outred = (float*)pool;           // aliases Xl after final barrier (8 KB)

  const int tid = threadIdx.x;
  const int lane = tid & 63;
  const int w = tid >> 6;       // wave 0..3
  const int G = lane >> 4;      // 0..3
  const int ln = lane & 15;

  // XCD-grouping swizzle (bijective on [0,2048))
  const int wg = blockIdx.x;
  const int xcd = wg & 7, j5 = wg >> 3;
  const int tb = (xcd << 1) | (j5 >> 7);
  const int bx = j5 & 127;

  {
    const float4* src = (const float4*)(Ximg + (size_t)bx * RB * DIM);
    float4* dst = (float4*)Xl;
    #pragma unroll
    for (int it = 0; it < 4; ++it) dst[tid + it * 256] = src[tid + it * 256];
  }
  biasl[tid] = biasPad[(size_t)tb * 256 + tid];
  __syncthreads();

  f32x4 out[4];
  #pragma unroll
  for (int nt = 0; nt < 4; ++nt)
    #pragma unroll
    for (int r = 0; r < 4; ++r) out[nt][r] = 0.f;

  const bool hiHalf = (G & 1);

  for (int sub = 0; sub < 2; ++sub) {
    const bf16x8* wf =
        (const bf16x8*)Wfrag + ((size_t)((tb*2 + sub)*4 + w) * 8) * 64;
    for (int p = 0; p < 2; ++p) {
      // ---- A fragments for this M-tile only (L2-resident stream) ----
      bf16x8 Afr[4];
      #pragma unroll
      for (int ks = 0; ks < 4; ++ks)
        Afr[ks] = wf[(p*4 + ks)*64 + lane];

      // ---- GEMM1: fv[slot][batch] for this M-tile ----
      f32x4 c1[4];
      #pragma unroll
      for (int nt = 0; nt < 4; ++nt)
        #pragma unroll
        for (int r = 0; r < 4; ++r) c1[nt][r] = 0.f;

      #pragma unroll
      for (int nt = 0; nt < 4; ++nt) {
        bf16x8 Bfr[4];
        #pragma unroll
        for (int ks = 0; ks < 4; ++ks) {
          int row = nt*16 + ln;
          int byte = row*256 + ((ks*64 + G*16) ^ ((row & 7) << 4));
          Bfr[ks] = *(const bf16x8*)(Xl + byte);
        }
        #pragma unroll
        for (int ks = 0; ks < 4; ++ks)
          c1[nt] = __builtin_amdgcn_mfma_f32_16x16x32_bf16(
              Afr[ks], Bfr[ks], c1[nt], 0, 0, 0);
      }

      // ---- epilogue: own-tree gates -> leaf fragments -> GEMM2 ----
      const int pg = tb*16 + sub*8 + 2*w + p;
      bf16x8 B2[4];
      #pragma unroll
      for (int ks = 0; ks < 4; ++ks)
        B2[ks] = ((const bf16x8*)Rb)[((size_t)pg*4 + ks)*64 + lane];
      const int treeloc = sub*16 + 4*w + 2*p + (G >> 1);
      float bv[6];
      #pragma unroll
      for (int d = 0; d < 6; ++d) bv[d] = biasl[treeloc*8 + d];

      #pragma unroll
      for (int nt = 0; nt < 4; ++nt) {
        // assemble own tree's 6 fv values (one xor16 half-merge)
        float fd[6];
        {
          float fva[4], fvb[4];
          #pragma unroll
          for (int r = 0; r < 4; ++r) {
            fva[r] = c1[nt][r];
            fvb[r] = __shfl_xor(c1[nt][r], 16);
          }
          #pragma unroll
          for (int r = 0; r < 4; ++r) fd[r] = hiHalf ? fvb[r] : fva[r];
          fd[4] = hiHalf ? fva[0] : fvb[0];
          fd[5] = hiHalf ? fva[1] : fvb[1];
        }
        float s[6], om[6];
        #pragma unroll
        for (int d = 0; d < 6; ++d) {
          float tl = fd[d] + bv[d];
          float sv = fminf(fmaxf(0.5f + 0.5f*tl, 0.f), 1.f);
          s[d] = sv; om[d] = 1.f - sv;
        }
        // depth 0-2 leaf products (bit=0 -> s, bit=1 -> om), folded with g3
        float q00 = s[0]*s[1],  q10 = om[0]*s[1];
        float q01 = s[0]*om[1], q11 = om[0]*om[1];
        float g3 = hiHalf ? om[3] : s[3];
        float s2g = s[2]*g3, o2g = om[2]*g3;
        float p3g[8];
        p3g[0]=q00*s2g; p3g[1]=q10*s2g; p3g[2]=q01*s2g; p3g[3]=q11*s2g;
        p3g[4]=q00*o2g; p3g[5]=q10*o2g; p3g[6]=q01*o2g; p3g[7]=q11*o2g;
        // ks -> (bit4=ks>>1, bit5=ks&1) common factors
        float c45[4];
        c45[0] = s[4]*s[5];  c45[1] = s[4]*om[5];
        c45[2] = om[4]*s[5]; c45[3] = om[4]*om[5];

        #pragma unroll
        for (int ks = 0; ks < 4; ++ks) {
          bf16x8 A;
          #pragma unroll
          for (int jj = 0; jj < 8; ++jj) A[jj] = (__bf16)(c45[ks] * p3g[jj]);
          out[nt] = __builtin_amdgcn_mfma_f32_16x16x32_bf16(
              A, B2[ks], out[nt], 0, 0, 0);
        }
      }
    }
  }

  // ---- cross-wave reduction (outred aliases Xl; all Xl reads done) ----
  __syncthreads();
  if (ln < UNITS) {
    #pragma unroll
    for (int nt = 0; nt < 4; ++nt)
      #pragma unroll
      for (int r = 0; r < 4; ++r)
        outred[((size_t)w*64 + nt*16 + 4*G + r)*8 + ln] = out[nt][r];
  }
  __syncthreads();
  #pragma unroll
  for (int v = 0; v < 2; ++v) {
    int e = tid + v*256;               // 0..511 = row*8+u
    int row = e >> 3, u = e & 7;
    float sum = outred[(0*64 + row)*8 + u]
              + outred[(1*64 + row)*8 + u]
              + outred[(2*64 + row)*8 + u]
              + outred[(3*64 + row)*8 + u];
    partial[((size_t)tb*BATCH + bx*RB + row)*8 + u] = sum;
  }
}

// ---------------------------------------------------------------------------
// reduce over the 16 tree-blocks, scale by 1/512
// ---------------------------------------------------------------------------
__global__ __launch_bounds__(256) void odt_reduce(
    const float* __restrict__ partial, float* __restrict__ out)
{
  int i = blockIdx.x * 256 + threadIdx.x;   // 0..65535
  float s = 0.f;
  #pragma unroll
  for (int t = 0; t < NTREEBLK; ++t)
    s += partial[(size_t)t * BATCH * UNITS + i];
  out[i] = s * (1.f / NTREES);
}

extern "C" void kernel_launch(void* const* d_in, const int* in_sizes, int n_in,
                              void* d_out, int out_size, void* d_ws, size_t ws_size,
                              hipStream_t stream)
{
  const float* inputs   = (const float*)d_in[0];
  const float* logits   = (const float*)d_in[1];
  const float* thr      = (const float*)d_in[2];
  const float* logtemp  = (const float*)d_in[3];
  const float* response = (const float*)d_in[4];
  float* out = (float*)d_out;

  char* ws = (char*)d_ws;
  unsigned short* Wfrag = (unsigned short*)(ws);                // 1 MB
  unsigned short* Ximg  = (unsigned short*)(ws + (1<<20));      // 2 MB
  unsigned short* Rb    = (unsigned short*)(ws + (3<<20));      // 1 MB
  float* biasPad        = (float*)(ws + (4<<20));               // 16 KB
  float* partial        = (float*)(ws + (4<<20) + (1<<14));     // 4 MB

  hipLaunchKernelGGL(prep_all, dim3(16384), dim3(128), 0, stream,
                     logits, thr, logtemp, inputs, response,
                     Wfrag, Ximg, Rb, biasPad);
  hipLaunchKernelGGL(odt_main, dim3(NROWBLK * NTREEBLK), dim3(256), 0, stream,
                     Ximg, Wfrag, biasPad, Rb, partial);
  hipLaunchKernelGGL(odt_reduce, dim3(BATCH * UNITS / 256), dim3(256), 0, stream,
                     partial, out);
}